// Round 1
// baseline (1912.693 us; speedup 1.0000x reference)
//
#include <hip/hip_runtime.h>

#define NNODES 800000
#define CINC   32
#define COUTC  64
#define KT     27
#define EPSV   1e-5f

typedef _Float16 half8 __attribute__((ext_vector_type(8)));
typedef _Float16 half4 __attribute__((ext_vector_type(4)));
typedef float    f32x4 __attribute__((ext_vector_type(4)));

#define MFMA(A, B, C) __builtin_amdgcn_mfma_f32_16x16x32_f16((A), (B), (C), 0, 0, 0)

// ---------------------------------------------------------------------------
// GroupNorm over one lane-local group of 4 channels (matches jnp reference).
// ---------------------------------------------------------------------------
__device__ __forceinline__ f32x4 gn4(f32x4 v, const float* __restrict__ w,
                                     const float* __restrict__ b, int cb) {
  const float mu = (v[0] + v[1] + v[2] + v[3]) * 0.25f;
  f32x4 d;
#pragma unroll
  for (int j = 0; j < 4; ++j) d[j] = v[j] - mu;
  const float var = (d[0] * d[0] + d[1] * d[1] + d[2] * d[2] + d[3] * d[3]) * 0.25f;
  const float rs = 1.0f / sqrtf(var + EPSV);
  const f32x4 wv = *(const f32x4*)(w + cb);
  const f32x4 bv = *(const f32x4*)(b + cb);
  f32x4 r;
#pragma unroll
  for (int j = 0; j < 4; ++j) r[j] = d[j] * rs * wv[j] + bv[j];
  return r;
}

// ---------------------------------------------------------------------------
// Prepass 1: split f32 -> f16 hi + f16 lo, PACKED per node:
// dpk[node][0..31] = hi, dpk[node][32..63] = lo  (one 128 B row per node).
// ---------------------------------------------------------------------------
__global__ __launch_bounds__(256) void k_split(const float* __restrict__ x,
                                               _Float16* __restrict__ dpk, int n4) {
  const int i = blockIdx.x * 256 + threadIdx.x;
  if (i >= n4) return;
  const f32x4 v = ((const f32x4*)x)[i];
  half4 h, l;
#pragma unroll
  for (int j = 0; j < 4; ++j) {
    h[j] = (_Float16)v[j];
    l[j] = (_Float16)(v[j] - (float)h[j]);
  }
  const int n = i >> 3, g = i & 7;  // node, 4-channel group
  *(half4*)(dpk + (size_t)n * 64 + g * 4) = h;
  *(half4*)(dpk + (size_t)n * 64 + 32 + g * 4) = l;
}

// ---------------------------------------------------------------------------
// Prepass 2: pre-swizzle weights into the MFMA A-operand image layout.
// waT: [27][t:4][h:2][lane:64][8 f16]   wbT: [27][t:4][kc:2][h:2][lane:64][8]
// w1T: [t:4][h:2][lane:64][8]
// lane l encodes: cout = 16*t + (l&15), cin chunk = (l>>4)*8 (+32*kc).
// A fragment read is a lane-contiguous 1024 B region -> a single perfectly
// coalesced wave load DIRECTLY FROM GLOBAL (L2-broadcast; no LDS staging).
// ---------------------------------------------------------------------------
__global__ __launch_bounds__(256) void k_prepw(const float* __restrict__ Wa,
                                               const float* __restrict__ Wb,
                                               const float* __restrict__ W1,
                                               _Float16* __restrict__ waT,
                                               _Float16* __restrict__ wbT,
                                               _Float16* __restrict__ w1T) {
  const int u = blockIdx.x * 256 + threadIdx.x;
  const float* s;
  _Float16* d;
  size_t db;
  int cin0, cout;
  if (u < 6912) {  // Wa: 27 taps * 4 tiles * 64 lanes
    const int tap = u >> 8, r = u & 255, t = r >> 6, l = r & 63;
    cin0 = (l >> 4) * 8;
    cout = t * 16 + (l & 15);
    s = Wa + (size_t)tap * CINC * COUTC;
    d = waT;
    db = ((size_t)(tap * 8 + t * 2) * 64 + l) * 8;
  } else if (u < 20736) {  // Wb: 27 * 4 * 2 kc * 64
    const int u2 = u - 6912;
    const int tap = u2 >> 9, r = u2 & 511, t = r >> 7, r2 = r & 127;
    const int kc = r2 >> 6, l = r2 & 63;
    cin0 = kc * 32 + (l >> 4) * 8;
    cout = t * 16 + (l & 15);
    s = Wb + (size_t)tap * COUTC * COUTC;
    d = wbT;
    db = ((size_t)(tap * 16 + t * 4 + kc * 2) * 64 + l) * 8;
  } else if (u < 20992) {  // W1: 4 * 64
    const int u3 = u - 20736, t = u3 >> 6, l = u3 & 63;
    cin0 = (l >> 4) * 8;
    cout = t * 16 + (l & 15);
    s = W1;
    d = w1T;
    db = ((size_t)(t * 2) * 64 + l) * 8;
  } else {
    return;
  }
  half8 h, l8;
#pragma unroll
  for (int j = 0; j < 8; ++j) {
    const float v = s[(size_t)(cin0 + j) * COUTC + cout];
    h[j] = (_Float16)v;
    l8[j] = (_Float16)(v - (float)h[j]);
  }
  *(half8*)(d + db) = h;          // hi plane
  *(half8*)(d + db + 512) = l8;   // lo plane (+64 lanes * 8)
}

// ---------------------------------------------------------------------------
// Kernel A: h = relu(GN(octree_conv(data, neigh, Wa))) -> packed f16 hi/lo.
// 4 waves, 128 nodes/block; wave = 32 nodes x 64 couts. No mid-kernel
// barriers: weights read directly from global (L2), gathers register
// ping-pong double-buffered across taps.
// ---------------------------------------------------------------------------
__global__ __launch_bounds__(256, 4) void k_conva(
    const _Float16* __restrict__ dpk, const int* __restrict__ neigh,
    const _Float16* __restrict__ waT, const float* __restrict__ gw,
    const float* __restrict__ gb, _Float16* __restrict__ hpk) {
  __shared__ int s_n[128 * KT];
  const int tid = threadIdx.x;
  const int wave = tid >> 6, lane = tid & 63;
  const int cl = lane & 15, q = lane >> 4;
  const int node0 = blockIdx.x * 128;

  for (int j = tid; j < 128 * KT; j += 256) s_n[j] = neigh[(size_t)node0 * KT + j];
  __syncthreads();

  f32x4 acc[4][2] = {};
  const int ln0 = wave * 32 + cl;
  const _Float16* wp = waT + lane * 8;

  auto gath = [&](int tap, half8& xh0, half8& xl0, half8& xh1, half8& xl1) {
    const int i0 = s_n[ln0 * KT + tap];
    const int i1 = s_n[(ln0 + 16) * KT + tap];
    const _Float16* p0 = dpk + (size_t)i0 * 64 + q * 8;
    const _Float16* p1 = dpk + (size_t)i1 * 64 + q * 8;
    xh0 = *(const half8*)(p0);
    xl0 = *(const half8*)(p0 + 32);
    xh1 = *(const half8*)(p1);
    xl1 = *(const half8*)(p1 + 32);
  };
  auto comp = [&](int tap, half8 xh0, half8 xl0, half8 xh1, half8 xl1) {
#pragma unroll
    for (int t = 0; t < 4; ++t) {
      const half8 wh = *(const half8*)(wp + (size_t)(tap * 8 + t * 2) * 512);
      const half8 wl = *(const half8*)(wp + (size_t)(tap * 8 + t * 2) * 512 + 512);
      acc[t][0] = MFMA(wh, xh0, acc[t][0]);
      acc[t][0] = MFMA(wh, xl0, acc[t][0]);
      acc[t][0] = MFMA(wl, xh0, acc[t][0]);
      acc[t][1] = MFMA(wh, xh1, acc[t][1]);
      acc[t][1] = MFMA(wh, xl1, acc[t][1]);
      acc[t][1] = MFMA(wl, xh1, acc[t][1]);
    }
  };

  half8 a0h, a0l, a1h, a1l, b0h, b0l, b1h, b1l;
  gath(0, a0h, a0l, a1h, a1l);
  for (int tap = 0; tap < KT; tap += 2) {
    if (tap + 1 < KT) gath(tap + 1, b0h, b0l, b1h, b1l);
    comp(tap, a0h, a0l, a1h, a1l);
    if (tap + 2 < KT) gath(tap + 2, a0h, a0l, a1h, a1l);
    if (tap + 1 < KT) comp(tap + 1, b0h, b0l, b1h, b1l);
  }

#pragma unroll
  for (int t = 0; t < 4; ++t)
#pragma unroll
    for (int nt = 0; nt < 2; ++nt) {
      const int node = node0 + wave * 32 + nt * 16 + cl;
      const int cb = t * 16 + q * 4;
      const f32x4 g = gn4(acc[t][nt], gw, gb, cb);
      half4 h, l;
#pragma unroll
      for (int j = 0; j < 4; ++j) {
        const float v = fmaxf(g[j], 0.0f);
        h[j] = (_Float16)v;
        l[j] = (_Float16)(v - (float)h[j]);
      }
      // packed: hpk[node][0..63]=hi, [64..127]=lo
      *(half4*)(hpk + (size_t)node * 128 + cb) = h;
      *(half4*)(hpk + (size_t)node * 128 + 64 + cb) = l;
    }
}

// ---------------------------------------------------------------------------
// Kernel B: out = relu(GN(octree_conv(h, neigh, Wb)) + GN(data @ W1)) -> f32.
// Same barrier-free, direct-global-weight, ping-pong structure.
// ---------------------------------------------------------------------------
__global__ __launch_bounds__(256, 3) void k_convb(
    const _Float16* __restrict__ hpk, const _Float16* __restrict__ dpk,
    const int* __restrict__ neigh, const _Float16* __restrict__ wbT,
    const _Float16* __restrict__ w1T,
    const float* __restrict__ gbw, const float* __restrict__ gbb,
    const float* __restrict__ gsw, const float* __restrict__ gsb,
    float* __restrict__ out) {
  __shared__ int s_n[128 * KT];
  const int tid = threadIdx.x;
  const int wave = tid >> 6, lane = tid & 63;
  const int cl = lane & 15, q = lane >> 4;
  const int node0 = blockIdx.x * 128;

  for (int j = tid; j < 128 * KT; j += 256) s_n[j] = neigh[(size_t)node0 * KT + j];
  __syncthreads();

  f32x4 acc[4][2] = {};
  const int ln0 = wave * 32 + cl;
  const _Float16* wp = wbT + lane * 8;

  auto gath = [&](int tap, half8& h0a, half8& h0b, half8& l0a, half8& l0b,
                  half8& h1a, half8& h1b, half8& l1a, half8& l1b) {
    const int i0 = s_n[ln0 * KT + tap];
    const int i1 = s_n[(ln0 + 16) * KT + tap];
    const _Float16* p0 = hpk + (size_t)i0 * 128 + q * 8;
    const _Float16* p1 = hpk + (size_t)i1 * 128 + q * 8;
    h0a = *(const half8*)(p0);
    h0b = *(const half8*)(p0 + 32);
    l0a = *(const half8*)(p0 + 64);
    l0b = *(const half8*)(p0 + 96);
    h1a = *(const half8*)(p1);
    h1b = *(const half8*)(p1 + 32);
    l1a = *(const half8*)(p1 + 64);
    l1b = *(const half8*)(p1 + 96);
  };
  auto comp = [&](int tap, half8 h0a, half8 h0b, half8 l0a, half8 l0b,
                  half8 h1a, half8 h1b, half8 l1a, half8 l1b) {
#pragma unroll
    for (int t = 0; t < 4; ++t) {
      const _Float16* wb0 = wp + (size_t)(tap * 16 + t * 4) * 512;
      const half8 wha = *(const half8*)(wb0);
      const half8 wla = *(const half8*)(wb0 + 512);
      const half8 whb = *(const half8*)(wb0 + 1024);
      const half8 wlb = *(const half8*)(wb0 + 1536);
      acc[t][0] = MFMA(wha, h0a, acc[t][0]);
      acc[t][0] = MFMA(wha, l0a, acc[t][0]);
      acc[t][0] = MFMA(wla, h0a, acc[t][0]);
      acc[t][0] = MFMA(whb, h0b, acc[t][0]);
      acc[t][0] = MFMA(whb, l0b, acc[t][0]);
      acc[t][0] = MFMA(wlb, h0b, acc[t][0]);
      acc[t][1] = MFMA(wha, h1a, acc[t][1]);
      acc[t][1] = MFMA(wha, l1a, acc[t][1]);
      acc[t][1] = MFMA(wla, h1a, acc[t][1]);
      acc[t][1] = MFMA(whb, h1b, acc[t][1]);
      acc[t][1] = MFMA(whb, l1b, acc[t][1]);
      acc[t][1] = MFMA(wlb, h1b, acc[t][1]);
    }
  };

  half8 a0, a1, a2, a3, a4, a5, a6, a7;
  half8 b0, b1, b2, b3, b4, b5, b6, b7;
  gath(0, a0, a1, a2, a3, a4, a5, a6, a7);
  for (int tap = 0; tap < KT; tap += 2) {
    if (tap + 1 < KT) gath(tap + 1, b0, b1, b2, b3, b4, b5, b6, b7);
    comp(tap, a0, a1, a2, a3, a4, a5, a6, a7);
    if (tap + 2 < KT) gath(tap + 2, a0, a1, a2, a3, a4, a5, a6, a7);
    if (tap + 1 < KT) comp(tap + 1, b0, b1, b2, b3, b4, b5, b6, b7);
  }

  // Shortcut: sc = data @ W1 (K=32, identity "tap" on own node).
  f32x4 sc[4][2] = {};
  {
    const int n0g = node0 + wave * 32 + cl;
    const _Float16* p0 = dpk + (size_t)n0g * 64 + q * 8;
    const _Float16* p1 = dpk + (size_t)(n0g + 16) * 64 + q * 8;
    const half8 sh0 = *(const half8*)(p0);
    const half8 sl0 = *(const half8*)(p0 + 32);
    const half8 sh1 = *(const half8*)(p1);
    const half8 sl1 = *(const half8*)(p1 + 32);
    const _Float16* w1p = w1T + lane * 8;
#pragma unroll
    for (int t = 0; t < 4; ++t) {
      const half8 wh = *(const half8*)(w1p + (size_t)(t * 2) * 512);
      const half8 wl = *(const half8*)(w1p + (size_t)(t * 2) * 512 + 512);
      sc[t][0] = MFMA(wh, sh0, sc[t][0]);
      sc[t][0] = MFMA(wh, sl0, sc[t][0]);
      sc[t][0] = MFMA(wl, sh0, sc[t][0]);
      sc[t][1] = MFMA(wh, sh1, sc[t][1]);
      sc[t][1] = MFMA(wh, sl1, sc[t][1]);
      sc[t][1] = MFMA(wl, sh1, sc[t][1]);
    }
  }

#pragma unroll
  for (int t = 0; t < 4; ++t)
#pragma unroll
    for (int nt = 0; nt < 2; ++nt) {
      const int node = node0 + wave * 32 + nt * 16 + cl;
      const int cb = t * 16 + q * 4;
      const f32x4 a = gn4(acc[t][nt], gbw, gbb, cb);
      const f32x4 s = gn4(sc[t][nt], gsw, gsb, cb);
      f32x4 o;
#pragma unroll
      for (int j = 0; j < 4; ++j) o[j] = fmaxf(a[j] + s[j], 0.0f);
      *(f32x4*)(out + (size_t)node * 64 + cb) = o;
    }
}

// ---------------------------------------------------------------------------
extern "C" void kernel_launch(void* const* d_in, const int* in_sizes, int n_in,
                              void* d_out, int out_size, void* d_ws, size_t ws_size,
                              hipStream_t stream) {
  const float* data = (const float*)d_in[0];
  const int* neigh = (const int*)d_in[1];
  const float* Wa = (const float*)d_in[2];
  const float* gaw = (const float*)d_in[3];
  const float* gab = (const float*)d_in[4];
  const float* Wb = (const float*)d_in[5];
  const float* gbw = (const float*)d_in[6];
  const float* gbb = (const float*)d_in[7];
  const float* W1 = (const float*)d_in[8];
  const float* gsw = (const float*)d_in[9];
  const float* gsb = (const float*)d_in[10];
  float* out = (float*)d_out;

  // Workspace layout (16B aligned), total ~307.9 MB (same as baseline):
  char* ws = (char*)d_ws;
  _Float16* dpk = (_Float16*)(ws);                  // 102,400,000 B  [N][hi32|lo32]
  _Float16* hpk = (_Float16*)(ws + 102400000);      // 204,800,000 B  [N][hi64|lo64]
  _Float16* waT = (_Float16*)(ws + 307200000);      //     221,184 B
  _Float16* wbT = (_Float16*)(ws + 307421184);      //     442,368 B
  _Float16* w1T = (_Float16*)(ws + 307863552);      //       8,192 B

  // Prepass
  k_split<<<25000, 256, 0, stream>>>(data, dpk, NNODES * CINC / 4);
  k_prepw<<<82, 256, 0, stream>>>(Wa, Wb, W1, waT, wbT, w1T);

  // conv3x3a + GN + ReLU -> h (packed f16 hi/lo)
  k_conva<<<NNODES / 128, 256, 0, stream>>>(dpk, neigh, waT, gaw, gab, hpk);

  // conv3x3b + GN, shortcut 1x1 + GN, add, ReLU -> out (f32)
  k_convb<<<NNODES / 128, 256, 0, stream>>>(hpk, dpk, neigh, wbT, w1T,
                                            gbw, gbb, gsw, gsb, out);
}

// Round 3
// 1605.814 us; speedup vs baseline: 1.1911x; 1.1911x over previous
//
#include <hip/hip_runtime.h>

#define NNODES 800000
#define CINC   32
#define COUTC  64
#define KT     27
#define EPSV   1e-5f

typedef _Float16 half8 __attribute__((ext_vector_type(8)));
typedef _Float16 half4 __attribute__((ext_vector_type(4)));
typedef float    f32x4 __attribute__((ext_vector_type(4)));

#define MFMA(A, B, C) __builtin_amdgcn_mfma_f32_16x16x32_f16((A), (B), (C), 0, 0, 0)
#define SBAR()  __builtin_amdgcn_s_barrier()
#define SCHED() __builtin_amdgcn_sched_barrier(0)

// Async global->LDS, 16 B per lane: global src per-lane, LDS dst uniform+lane*16.
__device__ __forceinline__ void gl2lds(const _Float16* g, _Float16* l) {
  __builtin_amdgcn_global_load_lds(
      (const __attribute__((address_space(1))) void*)g,
      (__attribute__((address_space(3))) void*)l, 16, 0, 0);
}

// ---------------------------------------------------------------------------
// GroupNorm over one lane-local group of 4 channels (matches jnp reference).
// ---------------------------------------------------------------------------
__device__ __forceinline__ f32x4 gn4(f32x4 v, const float* __restrict__ w,
                                     const float* __restrict__ b, int cb) {
  const float mu = (v[0] + v[1] + v[2] + v[3]) * 0.25f;
  f32x4 d;
#pragma unroll
  for (int j = 0; j < 4; ++j) d[j] = v[j] - mu;
  const float var = (d[0] * d[0] + d[1] * d[1] + d[2] * d[2] + d[3] * d[3]) * 0.25f;
  const float rs = 1.0f / sqrtf(var + EPSV);
  const f32x4 wv = *(const f32x4*)(w + cb);
  const f32x4 bv = *(const f32x4*)(b + cb);
  f32x4 r;
#pragma unroll
  for (int j = 0; j < 4; ++j) r[j] = d[j] * rs * wv[j] + bv[j];
  return r;
}

// ---------------------------------------------------------------------------
// Prepass 1: split f32 -> f16 hi + lo, packed per node (128 B row).
// ---------------------------------------------------------------------------
__global__ __launch_bounds__(256) void k_split(const float* __restrict__ x,
                                               _Float16* __restrict__ dpk, int n4) {
  const int i = blockIdx.x * 256 + threadIdx.x;
  if (i >= n4) return;
  const f32x4 v = ((const f32x4*)x)[i];
  half4 h, l;
#pragma unroll
  for (int j = 0; j < 4; ++j) {
    h[j] = (_Float16)v[j];
    l[j] = (_Float16)(v[j] - (float)h[j]);
  }
  const int n = i >> 3, g = i & 7;
  *(half4*)(dpk + (size_t)n * 64 + g * 4) = h;
  *(half4*)(dpk + (size_t)n * 64 + 32 + g * 4) = l;
}

// ---------------------------------------------------------------------------
// Prepass 2: pre-swizzle weights into MFMA A-operand image layout.
// waT: [27][t:4][h:2][lane:64][8]  wbT: [27][t:4][kc:2][h:2][lane:64][8]
// ---------------------------------------------------------------------------
__global__ __launch_bounds__(256) void k_prepw(const float* __restrict__ Wa,
                                               const float* __restrict__ Wb,
                                               const float* __restrict__ W1,
                                               _Float16* __restrict__ waT,
                                               _Float16* __restrict__ wbT,
                                               _Float16* __restrict__ w1T) {
  const int u = blockIdx.x * 256 + threadIdx.x;
  const float* s;
  _Float16* d;
  size_t db;
  int cin0, cout;
  if (u < 6912) {
    const int tap = u >> 8, r = u & 255, t = r >> 6, l = r & 63;
    cin0 = (l >> 4) * 8;
    cout = t * 16 + (l & 15);
    s = Wa + (size_t)tap * CINC * COUTC;
    d = waT;
    db = ((size_t)(tap * 8 + t * 2) * 64 + l) * 8;
  } else if (u < 20736) {
    const int u2 = u - 6912;
    const int tap = u2 >> 9, r = u2 & 511, t = r >> 7, r2 = r & 127;
    const int kc = r2 >> 6, l = r2 & 63;
    cin0 = kc * 32 + (l >> 4) * 8;
    cout = t * 16 + (l & 15);
    s = Wb + (size_t)tap * COUTC * COUTC;
    d = wbT;
    db = ((size_t)(tap * 16 + t * 4 + kc * 2) * 64 + l) * 8;
  } else if (u < 20992) {
    const int u3 = u - 20736, t = u3 >> 6, l = u3 & 63;
    cin0 = (l >> 4) * 8;
    cout = t * 16 + (l & 15);
    s = W1;
    d = w1T;
    db = ((size_t)(t * 2) * 64 + l) * 8;
  } else {
    return;
  }
  half8 h, l8;
#pragma unroll
  for (int j = 0; j < 8; ++j) {
    const float v = s[(size_t)(cin0 + j) * COUTC + cout];
    h[j] = (_Float16)v;
    l8[j] = (_Float16)(v - (float)h[j]);
  }
  *(half8*)(d + db) = h;
  *(half8*)(d + db + 512) = l8;
}

// ===========================================================================
// Kernel A: h = relu(GN(conv(data, Wa))) -> packed f16 hi/lo.
// Weights: LDS double-buffer via global_load_lds, counted vmcnt, raw
// s_barrier. ALL phase boundaries pinned with sched_barrier(0) so no
// memory op (ds_read / gl_lds / gather) crosses a phase edge (race fix).
// Gathers: 3 rotating VGPR buffers, depth-2 prefetch, static-indexed.
// ===========================================================================
#define STAGEA(T, SL)                                                          \
  {                                                                            \
    const _Float16* sp_ = waT + (size_t)(T)*4096 + (wave * 2) * 512 + lane * 8;\
    _Float16* dp_ = s_w + (SL)*4096 + (wave * 2) * 512;                        \
    gl2lds(sp_, dp_);                                                          \
    gl2lds(sp_ + 512, dp_ + 512);                                              \
  }

#define GATHA(T, GB)                                                           \
  {                                                                            \
    const int i0_ = s_n[ln0 * KT + (T)];                                       \
    const int i1_ = s_n[(ln0 + 16) * KT + (T)];                                \
    const _Float16* p0_ = dpk + (size_t)i0_ * 64 + q * 8;                      \
    const _Float16* p1_ = dpk + (size_t)i1_ * 64 + q * 8;                      \
    GB[0] = *(const half8*)(p0_);                                              \
    GB[1] = *(const half8*)(p0_ + 32);                                         \
    GB[2] = *(const half8*)(p1_);                                              \
    GB[3] = *(const half8*)(p1_ + 32);                                         \
  }

#define STEPA(T, S, GBC, GBN, VMS, DOSTAGE, DOG)                               \
  {                                                                            \
    SCHED();                                                                   \
    SBAR(); /* #1: all waves done reading slot 1-S */                          \
    SCHED();                                                                   \
    if (DOSTAGE) STAGEA((T) + 1, 1 - (S));                                     \
    if (DOG) GATHA((T) + 2, GBN);                                              \
    asm volatile("s_waitcnt vmcnt(" VMS ")" ::: "memory");                     \
    SCHED();                                                                   \
    SBAR(); /* #2: slot S fully staged by every wave */                        \
    SCHED();                                                                   \
    _Pragma("unroll") for (int t4 = 0; t4 < 4; ++t4) {                         \
      const _Float16* wb_ = s_w + (S)*4096 + (t4 * 2) * 512 + lane * 8;        \
      const half8 wh_ = *(const half8*)(wb_);                                  \
      const half8 wl_ = *(const half8*)(wb_ + 512);                            \
      acc[t4][0] = MFMA(wh_, GBC[0], acc[t4][0]);                              \
      acc[t4][0] = MFMA(wh_, GBC[1], acc[t4][0]);                              \
      acc[t4][0] = MFMA(wl_, GBC[0], acc[t4][0]);                              \
      acc[t4][1] = MFMA(wh_, GBC[2], acc[t4][1]);                              \
      acc[t4][1] = MFMA(wh_, GBC[3], acc[t4][1]);                              \
      acc[t4][1] = MFMA(wl_, GBC[2], acc[t4][1]);                              \
    }                                                                          \
  }

__global__ __launch_bounds__(256, 4) void k_conva(
    const _Float16* __restrict__ dpk, const int* __restrict__ neigh,
    const _Float16* __restrict__ waT, const float* __restrict__ gw,
    const float* __restrict__ gb, _Float16* __restrict__ hpk) {
  __shared__ int s_n[128 * KT];
  __shared__ _Float16 s_w[2 * 4096];  // 2 slots x 8 KB
  const int tid = threadIdx.x;
  const int wave = tid >> 6, lane = tid & 63;
  const int cl = lane & 15, q = lane >> 4;
  const int node0 = blockIdx.x * 128;

  for (int j = tid; j < 128 * KT; j += 256) s_n[j] = neigh[(size_t)node0 * KT + j];
  __syncthreads();  // full drain once; outstanding = 0 entering prologue

  f32x4 acc[4][2] = {};
  const int ln0 = wave * 32 + cl;
  half8 g0[4], g1[4], g2[4];

  // Prologue: stage(0)->slot0 (2 gl_lds), G(0)->g0, G(1)->g1  [10 outstanding]
  STAGEA(0, 0);
  GATHA(0, g0);
  GATHA(1, g1);

  // Steady: retain [G(t+1) 4, stage(t+1) 2, G(t+2) 4] = vmcnt(10).
  for (int c6 = 0; c6 < 24; c6 += 6) {
    STEPA(c6 + 0, 0, g0, g2, "10", 1, 1);
    STEPA(c6 + 1, 1, g1, g0, "10", 1, 1);
    STEPA(c6 + 2, 0, g2, g1, "10", 1, 1);
    STEPA(c6 + 3, 1, g0, g2, "10", 1, 1);
    STEPA(c6 + 4, 0, g1, g0, "10", 1, 1);
    STEPA(c6 + 5, 1, g2, g1, "10", 1, 1);
  }
  STEPA(24, 0, g0, g2, "10", 1, 1);
  STEPA(25, 1, g1, g0, "6", 1, 0);
  STEPA(26, 0, g2, g1, "0", 0, 0);

#pragma unroll
  for (int t = 0; t < 4; ++t)
#pragma unroll
    for (int nt = 0; nt < 2; ++nt) {
      const int node = node0 + wave * 32 + nt * 16 + cl;
      const int cb = t * 16 + q * 4;
      const f32x4 g = gn4(acc[t][nt], gw, gb, cb);
      half4 h, l;
#pragma unroll
      for (int j = 0; j < 4; ++j) {
        const float v = fmaxf(g[j], 0.0f);
        h[j] = (_Float16)v;
        l[j] = (_Float16)(v - (float)h[j]);
      }
      *(half4*)(hpk + (size_t)node * 128 + cb) = h;
      *(half4*)(hpk + (size_t)node * 128 + 64 + cb) = l;
    }
}

// ===========================================================================
// Kernel B: out = relu(GN(conv(h, Wb)) + GN(data @ W1)) -> f32.
// Same pinned-phase structure; weight slot 16 KB, gather 8 frags (256 B row).
// ===========================================================================
#define STAGEB(T, SL)                                                          \
  {                                                                            \
    const _Float16* sp_ = wbT + (size_t)(T)*8192 + (wave * 4) * 512 + lane * 8;\
    _Float16* dp_ = s_w + (SL)*8192 + (wave * 4) * 512;                        \
    gl2lds(sp_, dp_);                                                          \
    gl2lds(sp_ + 512, dp_ + 512);                                              \
    gl2lds(sp_ + 1024, dp_ + 1024);                                            \
    gl2lds(sp_ + 1536, dp_ + 1536);                                            \
  }

#define GATHB(T, GB)                                                           \
  {                                                                            \
    const int i0_ = s_n[ln0 * KT + (T)];                                       \
    const int i1_ = s_n[(ln0 + 16) * KT + (T)];                                \
    const _Float16* p0_ = hpk + (size_t)i0_ * 128 + q * 8;                     \
    const _Float16* p1_ = hpk + (size_t)i1_ * 128 + q * 8;                     \
    GB[0] = *(const half8*)(p0_);                                              \
    GB[1] = *(const half8*)(p0_ + 32);                                         \
    GB[2] = *(const half8*)(p0_ + 64);                                         \
    GB[3] = *(const half8*)(p0_ + 96);                                         \
    GB[4] = *(const half8*)(p1_);                                              \
    GB[5] = *(const half8*)(p1_ + 32);                                         \
    GB[6] = *(const half8*)(p1_ + 64);                                         \
    GB[7] = *(const half8*)(p1_ + 96);                                         \
  }

#define STEPB(T, S, GBC, GBN, VMS, DOSTAGE, DOG)                               \
  {                                                                            \
    SCHED();                                                                   \
    SBAR();                                                                    \
    SCHED();                                                                   \
    if (DOSTAGE) STAGEB((T) + 1, 1 - (S));                                     \
    if (DOG) GATHB((T) + 2, GBN);                                              \
    asm volatile("s_waitcnt vmcnt(" VMS ")" ::: "memory");                     \
    SCHED();                                                                   \
    SBAR();                                                                    \
    SCHED();                                                                   \
    _Pragma("unroll") for (int t4 = 0; t4 < 4; ++t4) {                         \
      const _Float16* wb_ = s_w + (S)*8192 + (t4 * 4) * 512 + lane * 8;        \
      const half8 wha_ = *(const half8*)(wb_);                                 \
      const half8 wla_ = *(const half8*)(wb_ + 512);                           \
      const half8 whb_ = *(const half8*)(wb_ + 1024);                          \
      const half8 wlb_ = *(const half8*)(wb_ + 1536);                          \
      acc[t4][0] = MFMA(wha_, GBC[0], acc[t4][0]);                             \
      acc[t4][0] = MFMA(wha_, GBC[2], acc[t4][0]);                             \
      acc[t4][0] = MFMA(wla_, GBC[0], acc[t4][0]);                             \
      acc[t4][0] = MFMA(whb_, GBC[1], acc[t4][0]);                             \
      acc[t4][0] = MFMA(whb_, GBC[3], acc[t4][0]);                             \
      acc[t4][0] = MFMA(wlb_, GBC[1], acc[t4][0]);                             \
      acc[t4][1] = MFMA(wha_, GBC[4], acc[t4][1]);                             \
      acc[t4][1] = MFMA(wha_, GBC[6], acc[t4][1]);                             \
      acc[t4][1] = MFMA(wla_, GBC[4], acc[t4][1]);                             \
      acc[t4][1] = MFMA(whb_, GBC[5], acc[t4][1]);                             \
      acc[t4][1] = MFMA(whb_, GBC[7], acc[t4][1]);                             \
      acc[t4][1] = MFMA(wlb_, GBC[5], acc[t4][1]);                             \
    }                                                                          \
  }

__global__ __launch_bounds__(256, 3) void k_convb(
    const _Float16* __restrict__ hpk, const _Float16* __restrict__ dpk,
    const int* __restrict__ neigh, const _Float16* __restrict__ wbT,
    const _Float16* __restrict__ w1T,
    const float* __restrict__ gbw, const float* __restrict__ gbb,
    const float* __restrict__ gsw, const float* __restrict__ gsb,
    float* __restrict__ out) {
  __shared__ int s_n[128 * KT];
  __shared__ _Float16 s_w[2 * 8192];  // 2 slots x 16 KB
  const int tid = threadIdx.x;
  const int wave = tid >> 6, lane = tid & 63;
  const int cl = lane & 15, q = lane >> 4;
  const int node0 = blockIdx.x * 128;

  for (int j = tid; j < 128 * KT; j += 256) s_n[j] = neigh[(size_t)node0 * KT + j];
  __syncthreads();

  f32x4 acc[4][2] = {};
  const int ln0 = wave * 32 + cl;
  half8 g0[8], g1[8], g2[8];

  // Prologue: stage(0) 4 gl_lds, G(0)->g0, G(1)->g1  [20 outstanding]
  STAGEB(0, 0);
  GATHB(0, g0);
  GATHB(1, g1);

  // Steady: retain [G(t+1) 8, stage(t+1) 4, G(t+2) 8] = vmcnt(20).
  for (int c6 = 0; c6 < 24; c6 += 6) {
    STEPB(c6 + 0, 0, g0, g2, "20", 1, 1);
    STEPB(c6 + 1, 1, g1, g0, "20", 1, 1);
    STEPB(c6 + 2, 0, g2, g1, "20", 1, 1);
    STEPB(c6 + 3, 1, g0, g2, "20", 1, 1);
    STEPB(c6 + 4, 0, g1, g0, "20", 1, 1);
    STEPB(c6 + 5, 1, g2, g1, "20", 1, 1);
  }
  STEPB(24, 0, g0, g2, "20", 1, 1);
  STEPB(25, 1, g1, g0, "12", 1, 0);
  STEPB(26, 0, g2, g1, "0", 0, 0);

  // Shortcut: sc = data @ W1 (own node).
  f32x4 sc[4][2] = {};
  {
    const int n0g = node0 + wave * 32 + cl;
    const _Float16* p0 = dpk + (size_t)n0g * 64 + q * 8;
    const _Float16* p1 = dpk + (size_t)(n0g + 16) * 64 + q * 8;
    const half8 sh0 = *(const half8*)(p0);
    const half8 sl0 = *(const half8*)(p0 + 32);
    const half8 sh1 = *(const half8*)(p1);
    const half8 sl1 = *(const half8*)(p1 + 32);
    const _Float16* w1p = w1T + lane * 8;
#pragma unroll
    for (int t = 0; t < 4; ++t) {
      const half8 wh = *(const half8*)(w1p + (size_t)(t * 2) * 512);
      const half8 wl = *(const half8*)(w1p + (size_t)(t * 2) * 512 + 512);
      sc[t][0] = MFMA(wh, sh0, sc[t][0]);
      sc[t][0] = MFMA(wh, sl0, sc[t][0]);
      sc[t][0] = MFMA(wl, sh0, sc[t][0]);
      sc[t][1] = MFMA(wh, sh1, sc[t][1]);
      sc[t][1] = MFMA(wh, sl1, sc[t][1]);
      sc[t][1] = MFMA(wl, sh1, sc[t][1]);
    }
  }

#pragma unroll
  for (int t = 0; t < 4; ++t)
#pragma unroll
    for (int nt = 0; nt < 2; ++nt) {
      const int node = node0 + wave * 32 + nt * 16 + cl;
      const int cb = t * 16 + q * 4;
      const f32x4 a = gn4(acc[t][nt], gbw, gbb, cb);
      const f32x4 s = gn4(sc[t][nt], gsw, gsb, cb);
      f32x4 o;
#pragma unroll
      for (int j = 0; j < 4; ++j) o[j] = fmaxf(a[j] + s[j], 0.0f);
      *(f32x4*)(out + (size_t)node * 64 + cb) = o;
    }
}

// ---------------------------------------------------------------------------
extern "C" void kernel_launch(void* const* d_in, const int* in_sizes, int n_in,
                              void* d_out, int out_size, void* d_ws, size_t ws_size,
                              hipStream_t stream) {
  const float* data = (const float*)d_in[0];
  const int* neigh = (const int*)d_in[1];
  const float* Wa = (const float*)d_in[2];
  const float* gaw = (const float*)d_in[3];
  const float* gab = (const float*)d_in[4];
  const float* Wb = (const float*)d_in[5];
  const float* gbw = (const float*)d_in[6];
  const float* gbb = (const float*)d_in[7];
  const float* W1 = (const float*)d_in[8];
  const float* gsw = (const float*)d_in[9];
  const float* gsb = (const float*)d_in[10];
  float* out = (float*)d_out;

  char* ws = (char*)d_ws;
  _Float16* dpk = (_Float16*)(ws);                  // 102,400,000 B
  _Float16* hpk = (_Float16*)(ws + 102400000);      // 204,800,000 B
  _Float16* waT = (_Float16*)(ws + 307200000);      //     221,184 B
  _Float16* wbT = (_Float16*)(ws + 307421184);      //     442,368 B
  _Float16* w1T = (_Float16*)(ws + 307863552);      //       8,192 B

  k_split<<<25000, 256, 0, stream>>>(data, dpk, NNODES * CINC / 4);
  k_prepw<<<82, 256, 0, stream>>>(Wa, Wb, W1, waT, wbT, w1T);

  k_conva<<<NNODES / 128, 256, 0, stream>>>(dpk, neigh, waT, gaw, gab, hpk);
  k_convb<<<NNODES / 128, 256, 0, stream>>>(hpk, dpk, neigh, wbT, w1T,
                                            gbw, gbb, gsw, gsb, out);
}